// Round 1
// baseline (801.516 us; speedup 1.0000x reference)
//
#include <hip/hip_runtime.h>

#define BB 4
#define SS 4096
#define DD 64
#define TQ 16
#define TK 64
#define SV 68   // V tile LDS stride (floats): 16B-aligned b128, 2-way-max conflicts
#define SP 72   // P tile LDS stride

__global__ __launch_bounds__(256) void attn_fwd(const float* __restrict__ Q,
                                                const float* __restrict__ V,
                                                float* __restrict__ ctx,
                                                float* __restrict__ attn,
                                                float* __restrict__ wsm,
                                                float* __restrict__ wsl) {
    __shared__ float Vt[TK * SV];
    __shared__ float Pt[TQ * SP];
    const int t    = threadIdx.x;
    const int qloc = t >> 4;    // 0..15 query within tile
    const int i16  = t & 15;    // 0..15 lane within query group
    const int b    = blockIdx.y;
    const int qg   = blockIdx.x * TQ + qloc;

    const float* Qrow = Q + ((size_t)b * SS + qg) * DD;
    float4 qv[16];
#pragma unroll
    for (int j = 0; j < 16; ++j) qv[j] = ((const float4*)Qrow)[j];

    float m = -1e30f, l = 0.f;
    float4 o = {0.f, 0.f, 0.f, 0.f};

    const float* Vb      = V    + (size_t)b * SS * DD;
    float*       attnRow = attn + ((size_t)b * SS + qg) * SS;

    for (int kt = 0; kt < SS / TK; ++kt) {
        // --- stage V tile (64 keys x 64 dims) into LDS, coalesced float4 ---
        const float4* Vg = (const float4*)(Vb + (size_t)kt * TK * DD);
#pragma unroll
        for (int c = 0; c < 4; ++c) {
            int f   = t + 256 * c;      // float4 index in tile: 64 rows x 16
            int row = f >> 4, c4 = f & 15;
            float4 v = Vg[f];
            *(float4*)&Vt[row * SV + c4 * 4] = v;
        }
        __syncthreads();

        // --- scores for 4 keys: k = i16 + 16*kk ---
        float s[4];
#pragma unroll
        for (int kk = 0; kk < 4; ++kk) {
            int k = i16 + 16 * kk;
            float acc = 0.f;
#pragma unroll
            for (int j = 0; j < 16; ++j) {
                float4 v = *(const float4*)&Vt[k * SV + j * 4];
                acc += qv[j].x * v.x + qv[j].y * v.y + qv[j].z * v.z + qv[j].w * v.w;
            }
            s[kk] = acc;
            attnRow[kt * TK + k] = acc;   // raw score; normalized by K2
        }

        // --- online softmax update (16-lane group shares one query row) ---
        float tmax = fmaxf(fmaxf(s[0], s[1]), fmaxf(s[2], s[3]));
#pragma unroll
        for (int msk = 8; msk >= 1; msk >>= 1)
            tmax = fmaxf(tmax, __shfl_xor(tmax, msk));
        float mn    = fmaxf(m, tmax);
        float alpha = __expf(m - mn);
        float p[4], psum = 0.f;
#pragma unroll
        for (int kk = 0; kk < 4; ++kk) { p[kk] = __expf(s[kk] - mn); psum += p[kk]; }
#pragma unroll
        for (int msk = 8; msk >= 1; msk >>= 1)
            psum += __shfl_xor(psum, msk);
        l = l * alpha + psum;
        m = mn;
        o.x *= alpha; o.y *= alpha; o.z *= alpha; o.w *= alpha;

#pragma unroll
        for (int kk = 0; kk < 4; ++kk)
            Pt[qloc * SP + i16 + 16 * kk] = p[kk];
        __syncthreads();

        // --- context accumulate: this thread owns dims 4*i16..+3 of row qloc ---
#pragma unroll 8
        for (int k = 0; k < TK; ++k) {
            float  pw = Pt[qloc * SP + k];
            float4 v  = *(const float4*)&Vt[k * SV + i16 * 4];
            o.x += pw * v.x; o.y += pw * v.y; o.z += pw * v.z; o.w += pw * v.w;
        }
        __syncthreads();
    }

    float invl = 1.f / l;
    float4 oc = {o.x * invl, o.y * invl, o.z * invl, o.w * invl};
    *(float4*)&ctx[((size_t)b * SS + qg) * DD + i16 * 4] = oc;
    if (i16 == 0) {
        wsm[(size_t)b * SS + qg] = m;
        wsl[(size_t)b * SS + qg] = l;
    }
}

__global__ __launch_bounds__(256) void attn_norm(float* __restrict__ attn,
                                                 const float* __restrict__ wsm,
                                                 const float* __restrict__ wsl) {
    const int r = blockIdx.x;
    const float m   = wsm[r];
    const float inv = 1.f / wsl[r];
    float4* row = (float4*)(attn + (size_t)r * SS);
    const int t = threadIdx.x;
#pragma unroll
    for (int c = 0; c < 4; ++c) {
        float4 v = row[t + 256 * c];
        v.x = __expf(v.x - m) * inv;
        v.y = __expf(v.y - m) * inv;
        v.z = __expf(v.z - m) * inv;
        v.w = __expf(v.w - m) * inv;
        row[t + 256 * c] = v;
    }
}

extern "C" void kernel_launch(void* const* d_in, const int* in_sizes, int n_in,
                              void* d_out, int out_size, void* d_ws, size_t ws_size,
                              hipStream_t stream) {
    const float* Q = (const float*)d_in[0];
    const float* V = (const float*)d_in[1];
    float* ctx  = (float*)d_out;
    float* attn = (float*)d_out + (size_t)BB * SS * DD;
    float* wsm  = (float*)d_ws;                 // B*S floats
    float* wsl  = wsm + (size_t)BB * SS;        // B*S floats

    attn_fwd<<<dim3(SS / TQ, BB), 256, 0, stream>>>(Q, V, ctx, attn, wsm, wsl);
    attn_norm<<<dim3(BB * SS), 256, 0, stream>>>(attn, wsm, wsl);
}

// Round 2
// 384.966 us; speedup vs baseline: 2.0820x; 2.0820x over previous
//
#include <hip/hip_runtime.h>

#define BB 4
#define SS 4096
#define DD 64
#define QB 32    // queries per block (2 query-waves x 16)
#define TK 64    // keys per tile
#define SV 72    // V LDS stride (halfs): rows 144B, 16B-aligned b128
#define SP 72    // P LDS stride (halfs)

typedef _Float16 h16;
typedef h16 half4_t __attribute__((ext_vector_type(4)));
typedef h16 half8_t __attribute__((ext_vector_type(8)));
typedef float f32x4 __attribute__((ext_vector_type(4)));

struct LdsBufs {
    h16 Vhi[2][TK * SV];   // V tile f16 hi, [key][d]
    h16 Vlo[2][TK * SV];   // V tile f16 lo (f16x2 split)
    h16 VTr[2][DD * SV];   // V tile transposed, [d][key] (hi only, for P·V)
    h16 Pl[4][16 * SP];    // per-wave P tile, [q][key]
};

__device__ __forceinline__ void stage(LdsBufs& L, const float* Vb, int it, int t,
                                      bool with_vt) {
    const int ts  = t >> 7;      // tile slot 0/1 (tiles 2*it, 2*it+1)
    const int tt  = t & 127;
    const int c16 = tt & 15;     // float4 column
    const int kr  = tt >> 4;     // row group 0..7
    const f32x4* Vg = (const f32x4*)(Vb + ((size_t)(it * 2 + ts) * TK + kr * 8) * DD);
    half4_t hh[8];
#pragma unroll
    for (int i = 0; i < 8; ++i) {
        f32x4 v = Vg[i * 16 + c16];
        half4_t hi, lo;
#pragma unroll
        for (int j = 0; j < 4; ++j) {
            float x = v[j];
            h16 h = (h16)x;
            hi[j] = h;
            lo[j] = (h16)(x - (float)h);   // exact residual (Sterbenz)
        }
        hh[i] = hi;
        *(half4_t*)&L.Vhi[ts][(kr * 8 + i) * SV + c16 * 4] = hi;
        *(half4_t*)&L.Vlo[ts][(kr * 8 + i) * SV + c16 * 4] = lo;
    }
    if (with_vt) {
#pragma unroll
        for (int j = 0; j < 4; ++j) {
            half8_t col;
#pragma unroll
            for (int i = 0; i < 8; ++i) col[i] = hh[i][j];
            *(half8_t*)&L.VTr[ts][(c16 * 4 + j) * SV + kr * 8] = col;
        }
    }
}

// S^T = V * Q^T, f16x2-split scores (error ~2^-20): 24 MFMA per wave-tile.
__device__ __forceinline__ void scores(const LdsBufs& L, int ts, int qi, int quad,
                                       const half8_t* qhi, const half8_t* qlo,
                                       f32x4* sc) {
#pragma unroll
    for (int mt = 0; mt < 4; ++mt) sc[mt] = (f32x4){0.f, 0.f, 0.f, 0.f};
#pragma unroll
    for (int ks = 0; ks < 2; ++ks) {
#pragma unroll
        for (int mt = 0; mt < 4; ++mt) {
            half8_t ahi = *(const half8_t*)&L.Vhi[ts][(mt * 16 + qi) * SV + ks * 32 + quad * 8];
            half8_t alo = *(const half8_t*)&L.Vlo[ts][(mt * 16 + qi) * SV + ks * 32 + quad * 8];
            sc[mt] = __builtin_amdgcn_mfma_f32_16x16x32_f16(ahi, qhi[ks], sc[mt], 0, 0, 0);
            sc[mt] = __builtin_amdgcn_mfma_f32_16x16x32_f16(ahi, qlo[ks], sc[mt], 0, 0, 0);
            sc[mt] = __builtin_amdgcn_mfma_f32_16x16x32_f16(alo, qhi[ks], sc[mt], 0, 0, 0);
        }
    }
}

__global__ __launch_bounds__(256, 2) void attn_fused(const float* __restrict__ Q,
                                                     const float* __restrict__ V,
                                                     float* __restrict__ ctx,
                                                     float* __restrict__ attn) {
    __shared__ LdsBufs L;
    const int t     = threadIdx.x;
    const int w     = t >> 6;
    const int lane  = t & 63;
    const int qi    = lane & 15;   // this lane's query (C col) / A-row index
    const int quad  = lane >> 4;   // 0..3
    const int qgrp  = w & 1;       // query group within block
    const int khalf = w >> 1;      // key-tile parity (split-K)
    const int b     = blockIdx.y;
    const int qb    = blockIdx.x * QB + qgrp * 16;

    const float* Vb   = V + (size_t)b * SS * DD;
    const float* Qrow = Q + ((size_t)b * SS + qb + qi) * DD;

    // Q fragments, f16x2: B[k=d][n=q]: lane holds Q[qi][ks*32 + quad*8 + j]
    half8_t qhi[2], qlo[2];
#pragma unroll
    for (int ks = 0; ks < 2; ++ks) {
        const float* p = Qrow + ks * 32 + quad * 8;
#pragma unroll
        for (int j = 0; j < 8; ++j) {
            float x = p[j];
            h16 h = (h16)x;
            qhi[ks][j] = h;
            qlo[ks][j] = (h16)(x - (float)h);
        }
    }

    float mrun = -1e30f, lrun = 0.f;
    f32x4 oc[4];
#pragma unroll
    for (int mt = 0; mt < 4; ++mt) oc[mt] = (f32x4){0.f, 0.f, 0.f, 0.f};

    // ---------------- Phase 1: online softmax, ctx accumulate ----------------
    for (int it = 0; it < SS / TK / 2; ++it) {
        __syncthreads();
        stage(L, Vb, it, t, true);
        __syncthreads();

        f32x4 sc[4];
        scores(L, khalf, qi, quad, qhi, qlo, sc);

        float tmax = -1e30f;
#pragma unroll
        for (int mt = 0; mt < 4; ++mt)
#pragma unroll
            for (int r = 0; r < 4; ++r) tmax = fmaxf(tmax, sc[mt][r]);
        tmax = fmaxf(tmax, __shfl_xor(tmax, 16));
        tmax = fmaxf(tmax, __shfl_xor(tmax, 32));
        float mn    = fmaxf(mrun, tmax);
        float alpha = __expf(mrun - mn);
        float psum  = 0.f;
        half4_t pv[4];
#pragma unroll
        for (int mt = 0; mt < 4; ++mt)
#pragma unroll
            for (int r = 0; r < 4; ++r) {
                float p = __expf(sc[mt][r] - mn);
                psum += p;
                pv[mt][r] = (h16)p;
            }
        psum += __shfl_xor(psum, 16);
        psum += __shfl_xor(psum, 32);
        lrun = lrun * alpha + psum;
        mrun = mn;
#pragma unroll
        for (int mt = 0; mt < 4; ++mt) {
            oc[mt] *= alpha;
            // C row = quad*4+reg = key-within-mt; write transposed -> [q][key] contiguous
            *(half4_t*)&L.Pl[w][qi * SP + mt * 16 + quad * 4] = pv[mt];
        }

        // O^T += V^T * P^T : A = VTr[d][key], B = Pl[q][key]; C col = q (= qi)
#pragma unroll
        for (int ks = 0; ks < 2; ++ks) {
            half8_t bp = *(const half8_t*)&L.Pl[w][qi * SP + ks * 32 + quad * 8];
#pragma unroll
            for (int mt = 0; mt < 4; ++mt) {
                half8_t av = *(const half8_t*)&L.VTr[khalf][(mt * 16 + qi) * SV + ks * 32 + quad * 8];
                oc[mt] = __builtin_amdgcn_mfma_f32_16x16x32_f16(av, bp, oc[mt], 0, 0, 0);
            }
        }
    }

    // ---------------- Merge split-K partners (waves w and w^2) ----------------
    __syncthreads();
    {
        float* buf  = (float*)&L.Vhi[0][0];   // 4*64*18*4 = 18432 B fits in Vhi
        float* mine = buf + (w * 64 + lane) * 18;
        mine[0] = mrun;
        mine[1] = lrun;
#pragma unroll
        for (int mt = 0; mt < 4; ++mt)
#pragma unroll
            for (int r = 0; r < 4; ++r) mine[2 + mt * 4 + r] = oc[mt][r];
        __syncthreads();
        const float* po = buf + ((w ^ 2) * 64 + lane) * 18;
        float m2 = po[0], l2 = po[1];
        float mn = fmaxf(mrun, m2);
        float ea = __expf(mrun - mn), eb = __expf(m2 - mn);
        lrun = lrun * ea + l2 * eb;
#pragma unroll
        for (int mt = 0; mt < 4; ++mt)
#pragma unroll
            for (int r = 0; r < 4; ++r)
                oc[mt][r] = oc[mt][r] * ea + po[2 + mt * 4 + r] * eb;
        mrun = mn;
    }

    const float invl = 1.f / lrun;

    // ctx write (one wave per query group): O^T lane holds d = mt*16+quad*4+r for q=qi
    if (khalf == 0) {
        float* crow = ctx + ((size_t)b * SS + qb + qi) * DD;
#pragma unroll
        for (int mt = 0; mt < 4; ++mt) {
            f32x4 cv;
#pragma unroll
            for (int r = 0; r < 4; ++r) cv[r] = oc[mt][r] * invl;
            *(f32x4*)&crow[mt * 16 + quad * 4] = cv;
        }
    }

    // ---------------- Phase 2: recompute scores, write normalized weights ----
    float* arow = attn + ((size_t)b * SS + qb + qi) * SS;
    for (int it = 0; it < SS / TK / 2; ++it) {
        __syncthreads();
        stage(L, Vb, it, t, false);
        __syncthreads();

        f32x4 sc[4];
        scores(L, khalf, qi, quad, qhi, qlo, sc);
        const int kt = it * 2 + khalf;
#pragma unroll
        for (int mt = 0; mt < 4; ++mt) {
            f32x4 wv;
#pragma unroll
            for (int r = 0; r < 4; ++r) wv[r] = __expf(sc[mt][r] - mrun) * invl;
            *(f32x4*)&arow[kt * TK + mt * 16 + quad * 4] = wv;
        }
    }
}

extern "C" void kernel_launch(void* const* d_in, const int* in_sizes, int n_in,
                              void* d_out, int out_size, void* d_ws, size_t ws_size,
                              hipStream_t stream) {
    const float* Q = (const float*)d_in[0];
    const float* V = (const float*)d_in[1];
    float* ctx  = (float*)d_out;
    float* attn = (float*)d_out + (size_t)BB * SS * DD;
    attn_fused<<<dim3(SS / QB, BB), 256, 0, stream>>>(Q, V, ctx, attn);
}